// Round 11
// baseline (267.551 us; speedup 1.0000x reference)
//
#include <hip/hip_runtime.h>
#include <hip/hip_bf16.h>
#include <hip/hip_fp16.h>

typedef __attribute__((ext_vector_type(8))) _Float16 half8;
typedef __attribute__((ext_vector_type(2))) __fp16 fp16x2;
typedef __attribute__((ext_vector_type(4))) float f32x4;
typedef __attribute__((ext_vector_type(16))) float f32x16;

#define N_B 8
#define C_DIM 256
#define S_DIM 4096

__device__ __forceinline__ _Float16 f2h(float f) { return (_Float16)f; }

__device__ __forceinline__ f32x4 mfma16(half8 a, half8 b, f32x4 c) {
  return __builtin_amdgcn_mfma_f32_16x16x32_f16(a, b, c, 0, 0, 0);
}
__device__ __forceinline__ f32x16 mfma32(half8 a, half8 b, f32x16 c) {
  return __builtin_amdgcn_mfma_f32_32x32x16_f16(a, b, c, 0, 0, 0);
}

__device__ __forceinline__ void glds16(const _Float16* src, _Float16* dst) {
  __builtin_amdgcn_global_load_lds(
      (const __attribute__((address_space(1))) void*)src,
      (__attribute__((address_space(3))) void*)dst, 16, 0, 0);
}

__device__ __forceinline__ uint32_t pkrtz(float a, float b) {
  union { fp16x2 h; uint32_t u; } cv;
  cv.h = __builtin_amdgcn_cvt_pkrtz(a, b);
  return cv.u;
}

__device__ __forceinline__ float fexp2(float x) {
  return __builtin_amdgcn_exp2f(x);
}

// ---- K0: transpose x (n,C,S) fp32 -> xT (n,S,C) fp16 ----
__global__ __launch_bounds__(256) void k_transpose(const float* __restrict__ x,
                                                   _Float16* __restrict__ xT) {
  __shared__ _Float16 tile[64][65];
  int n = blockIdx.z, cb = blockIdx.y * 64, sb = blockIdx.x * 64;
  const float* xp = x + ((size_t)n * C_DIM + cb) * S_DIM + sb;
  int t = threadIdx.x;
#pragma unroll
  for (int p = 0; p < 4; ++p) {
    int row = p * 16 + (t >> 4);
    int col = (t & 15) * 4;
    float4 v4 = *(const float4*)(xp + (size_t)row * S_DIM + col);
    tile[row][col + 0] = f2h(v4.x);
    tile[row][col + 1] = f2h(v4.y);
    tile[row][col + 2] = f2h(v4.z);
    tile[row][col + 3] = f2h(v4.w);
  }
  __syncthreads();
  _Float16* op = xT + ((size_t)n * S_DIM + sb) * C_DIM + cb;
#pragma unroll
  for (int p = 0; p < 2; ++p) {
    int srow = p * 32 + (t >> 3);
    int ccol = (t & 7) * 8;
    half8 u;
#pragma unroll
    for (int i = 0; i < 8; ++i) u[i] = tile[ccol + i][srow];
    *(half8*)(op + (size_t)srow * C_DIM + ccol) = u;
  }
}

// ---- K0b: weights fp32 -> fp16; Wq pre-scaled by log2(e) ----
__global__ __launch_bounds__(256) void k_wconv(const float* __restrict__ w0, const float* __restrict__ w1,
                                               const float* __restrict__ w2, const float* __restrict__ w3,
                                               _Float16* __restrict__ Wh) {
  int idx = blockIdx.x * 256 + threadIdx.x;
  const float* srcs[4] = {w0, w1, w2, w3};
#pragma unroll
  for (int j = 0; j < 4; ++j) {
    const float* s = srcs[j];
    float sc = (j == 0) ? 1.4426950408889634f : 1.0f;
    for (int i = idx; i < C_DIM * C_DIM; i += 16384) Wh[j * C_DIM * C_DIM + i] = f2h(s[i] * sc);
  }
}

// ---- K1: projection GEMMs ----
__global__ __launch_bounds__(256) void k_proj(const _Float16* __restrict__ xT, const _Float16* __restrict__ Wh,
                                              _Float16* __restrict__ qT, _Float16* __restrict__ kT,
                                              _Float16* __restrict__ vv, float* __restrict__ outp) {
  __shared__ __align__(16) _Float16 As[128][72];
  __shared__ __align__(16) _Float16 Bs[128][72];
  int job = blockIdx.y;
  int n = job >> 2, j = job & 3;
  const _Float16* A;
  const _Float16* B;
  int tm, tn, ldo;
  _Float16* obf = nullptr;
  float* of32 = nullptr;
  const _Float16* xTn = xT + (size_t)n * S_DIM * C_DIM;
  if (j < 2) {
    A = xTn;
    B = Wh + j * C_DIM * C_DIM;
    tm = blockIdx.x >> 1; tn = blockIdx.x & 1;
    obf = (j == 0 ? qT : kT) + (size_t)n * S_DIM * C_DIM;
    ldo = C_DIM;
  } else {
    A = Wh + j * C_DIM * C_DIM;
    B = xTn;
    tm = blockIdx.x >> 5; tn = blockIdx.x & 31;
    ldo = S_DIM;
    if (j == 2) obf = vv + (size_t)n * C_DIM * S_DIM;
    else of32 = outp + (size_t)n * C_DIM * S_DIM;
  }
  int t = threadIdx.x, w = t >> 6, lane = t & 63, r = lane & 15, q = lane >> 4;
  int wm = w >> 1, wn = w & 1;
  f32x4 acc[4][4] = {};
  for (int kc = 0; kc < 4; ++kc) {
#pragma unroll
    for (int p = 0; p < 4; ++p) {
      int row = p * 32 + (t >> 3), c8 = (t & 7) * 8;
      *(half8*)&As[row][c8] = *(const half8*)(A + (size_t)(tm * 128 + row) * C_DIM + kc * 64 + c8);
      *(half8*)&Bs[row][c8] = *(const half8*)(B + (size_t)(tn * 128 + row) * C_DIM + kc * 64 + c8);
    }
    __syncthreads();
#pragma unroll
    for (int kk = 0; kk < 2; ++kk) {
      half8 a[4], b[4];
#pragma unroll
      for (int mi = 0; mi < 4; ++mi) a[mi] = *(const half8*)&As[wm * 64 + mi * 16 + r][kk * 32 + q * 8];
#pragma unroll
      for (int ni = 0; ni < 4; ++ni) b[ni] = *(const half8*)&Bs[wn * 64 + ni * 16 + r][kk * 32 + q * 8];
#pragma unroll
      for (int mi = 0; mi < 4; ++mi)
#pragma unroll
        for (int ni = 0; ni < 4; ++ni)
          acc[mi][ni] = mfma16(a[mi], b[ni], acc[mi][ni]);
    }
    __syncthreads();
  }
#pragma unroll
  for (int mi = 0; mi < 4; ++mi)
#pragma unroll
    for (int ni = 0; ni < 4; ++ni)
#pragma unroll
      for (int jj = 0; jj < 4; ++jj) {
        int row = tm * 128 + wm * 64 + mi * 16 + q * 4 + jj;
        int col = tn * 128 + wn * 64 + ni * 16 + r;
        float val = acc[mi][ni][jj];
        if (obf) obf[(size_t)row * ldo + col] = f2h(val);
        else of32[(size_t)row * ldo + col] = val;
      }
}

// ---- K2: partial row sums (base-2 scores; builtin exp2; hoisted addrs) ----
__global__ __launch_bounds__(512, 2) void k_rowsum(const _Float16* __restrict__ qT,
                                                   const _Float16* __restrict__ kT,
                                                   float* __restrict__ lpart) {
  __shared__ __align__(16) _Float16 Qs[2][64 * 256];
  int bid = blockIdx.x;
  int n = bid & 7, rest = bid >> 3;
  int tb = rest & 7, sq = rest >> 3;
  int t = threadIdx.x, w = t >> 6, lane = t & 63, r = lane & 15, q = lane >> 4;
  const _Float16* kp = kT + ((size_t)n * S_DIM + tb * 512 + w * 64) * C_DIM;
  const _Float16* qp = qT + ((size_t)n * S_DIM + sq * 1024) * C_DIM;
  half8 kf[4][8];
#pragma unroll
  for (int mt = 0; mt < 4; ++mt)
#pragma unroll
    for (int k = 0; k < 8; ++k)
      kf[mt][k] = *(const half8*)(kp + (size_t)(mt * 16 + r) * C_DIM + k * 32 + q * 8);
  int d0 = w * 1024 + lane * 16;
  int qswz = d0 ^ ((((w * 2) + (lane >> 5)) & 7) << 4);
  const char* qsrc0 = (const char*)qp + qswz;
  int rb = r * 256, rx = (r & 7) << 3, qq8 = q * 8;
  int kx[8];
#pragma unroll
  for (int k = 0; k < 8; ++k) kx[k] = (k * 32 + qq8) ^ rx;
#pragma unroll
  for (int i = 0; i < 4; ++i)
    glds16((const _Float16*)(qsrc0 + i * 8192), &Qs[0][i * 4096 + w * 512]);
  asm volatile("s_waitcnt vmcnt(0)" ::: "memory");
  __builtin_amdgcn_s_barrier();
  float sums[4][4] = {};
  for (int sc = 0; sc < 16; ++sc) {
    int cur = sc & 1, nxt = cur ^ 1;
    int sn = (sc + 1) & 15;
    const char* qb = qsrc0 + (size_t)sn * 32768;
#pragma unroll
    for (int i = 0; i < 4; ++i)
      glds16((const _Float16*)(qb + i * 8192), &Qs[nxt][i * 4096 + w * 512]);
    __builtin_amdgcn_s_setprio(1);
#pragma unroll
    for (int st = 0; st < 4; ++st) {
      f32x4 acc[4] = {};
#pragma unroll
      for (int k = 0; k < 8; ++k) {
        half8 b = *(const half8*)&Qs[cur][rb + st * 4096 + kx[k]];
#pragma unroll
        for (int mt = 0; mt < 4; ++mt) acc[mt] = mfma16(kf[mt][k], b, acc[mt]);
      }
#pragma unroll
      for (int mt = 0; mt < 4; ++mt)
#pragma unroll
        for (int jj = 0; jj < 4; ++jj) sums[mt][jj] += fexp2(acc[mt][jj]);
    }
    __builtin_amdgcn_s_setprio(0);
    asm volatile("s_waitcnt vmcnt(0) lgkmcnt(0)" ::: "memory");
    __builtin_amdgcn_s_barrier();
  }
#pragma unroll
  for (int mt = 0; mt < 4; ++mt)
#pragma unroll
    for (int jj = 0; jj < 4; ++jj) {
      float v = sums[mt][jj];
      v += __shfl_xor(v, 1);
      v += __shfl_xor(v, 2);
      v += __shfl_xor(v, 4);
      v += __shfl_xor(v, 8);
      if (r == 0)
        lpart[((size_t)sq * N_B + n) * S_DIM + tb * 512 + w * 64 + mt * 16 + q * 4 + jj] = v;
    }
}

// ---- K2b: fold 1/l into V ----
__global__ __launch_bounds__(256) void k_vscale(_Float16* __restrict__ vv, const float* __restrict__ lpart) {
  int idx = blockIdx.x * 256 + threadIdx.x;
  int t8 = idx & 511;
  int cn = idx >> 9;
  int n = cn >> 8;
  size_t voff = (size_t)cn * S_DIM + t8 * 8;
  half8 v = *(half8*)(vv + voff);
  const float* lp = lpart + (size_t)n * S_DIM + t8 * 8;
#pragma unroll
  for (int j = 0; j < 8; ++j) {
    float s = lp[j] + lp[N_B * S_DIM + j] + lp[2 * N_B * S_DIM + j] + lp[3 * N_B * S_DIM + j];
    v[j] = f2h((float)v[j] * (4096.0f / s));
  }
  *(half8*)(vv + voff) = v;
}

// ---- K3: attention, 8 waves (4 producers t32xs64 + 4 consumers c64xs128) ----
// 512 thr, launch_bounds(512,2) -> 256 unified regs/wave. LDS reads/iter:
// K 64 + V 32 + P 64 = 160 b128 (was 256). glds issued post-barrier (in compute
// phase, full phase of flight time); vmcnt(0) at top is then latency-free.
__global__ __launch_bounds__(512, 2) void k_attn(const _Float16* __restrict__ qT,
                                                 const _Float16* __restrict__ kT,
                                                 const _Float16* __restrict__ vv,
                                                 float* __restrict__ outp) {
  __shared__ __align__(16) _Float16 Kb[2][16384];  // [t64][c256] XOR-swz(32)
  __shared__ __align__(16) _Float16 Vb[2][16384];  // [c256][t64] XOR-swz(8)
  __shared__ __align__(16) _Float16 Pb[2][8192];   // [slot4][sblk4][lane64][8]
  int bid = blockIdx.x;
  int n = bid & 7, sb = bid >> 3;
  int tid = threadIdx.x, w = tid >> 6, lane = tid & 63;
  int l31 = lane & 31, h = lane >> 5;
  const _Float16* kpn = kT + (size_t)n * S_DIM * C_DIM;
  const _Float16* vvn = vv + (size_t)n * C_DIM * S_DIM;

  if (w < 4) {
    // ================= producers: t-block tp (32), s-blocks sp*2, sp*2+1 ====
    int tp = w >> 1, sp = w & 1;
    const _Float16* qp = qT + ((size_t)n * S_DIM + sb * 128 + sp * 64) * C_DIM;
    half8 qreg[2][16];
#pragma unroll
    for (int Y = 0; Y < 2; ++Y)
#pragma unroll
      for (int cs = 0; cs < 16; ++cs)
        qreg[Y][cs] = *(const half8*)(qp + (size_t)(Y * 32 + l31) * C_DIM + cs * 16 + h * 8);
    // K staging: 8 units/wave, rows r = w*16 + i*2 + h
    int koff[8];
#pragma unroll
    for (int i = 0; i < 8; ++i) {
      int r = w * 16 + i * 2 + h;
      koff[i] = r * C_DIM + ((l31 ^ (r & 31)) * 8);
    }
    int tko = (tp * 32 + l31) * C_DIM;
    int kaddr[16];
#pragma unroll
    for (int cs = 0; cs < 16; ++cs) kaddr[cs] = tko + 8 * ((2 * cs + h) ^ l31);
    // prologue: issue K(0)
#pragma unroll
    for (int i = 0; i < 8; ++i) glds16(kpn + koff[i], &Kb[0][w * 4096 + i * 512]);
    for (int it = 0; it <= 64; ++it) {
      asm volatile("s_waitcnt vmcnt(0) lgkmcnt(0)" ::: "memory");
      __builtin_amdgcn_s_barrier();
      if (it < 64) {
        // issue K(it+1) first (flies during this compute phase)
        if (it < 63) {
          const _Float16* kb = kpn + (size_t)(it + 1) * 64 * C_DIM;
          _Float16* kd = &Kb[(it + 1) & 1][0];
#pragma unroll
          for (int i = 0; i < 8; ++i) glds16(kb + koff[i], kd + w * 4096 + i * 512);
        }
        const _Float16* kc = &Kb[it & 1][0];
        f32x16 pacc0, pacc1;
#pragma unroll
        for (int i = 0; i < 16; ++i) { pacc0[i] = -4.0f; pacc1[i] = -4.0f; }
        __builtin_amdgcn_s_setprio(1);
#pragma unroll
        for (int cs = 0; cs < 16; ++cs) {
          half8 a = *(const half8*)(kc + kaddr[cs]);
          pacc0 = mfma32(a, qreg[0][cs], pacc0);
          pacc1 = mfma32(a, qreg[1][cs], pacc1);
        }
        __builtin_amdgcn_s_setprio(0);
        _Float16* pd = &Pb[it & 1][0];
#pragma unroll
        for (int Y = 0; Y < 2; ++Y) {
          const f32x16& pa = Y ? pacc1 : pacc0;
          uint32_t p0 = pkrtz(fexp2(pa[0]), fexp2(pa[1]));
          uint32_t p1 = pkrtz(fexp2(pa[2]), fexp2(pa[3]));
          uint32_t p2 = pkrtz(fexp2(pa[4]), fexp2(pa[5]));
          uint32_t p3 = pkrtz(fexp2(pa[6]), fexp2(pa[7]));
          uint32_t p4 = pkrtz(fexp2(pa[8]), fexp2(pa[9]));
          uint32_t p5 = pkrtz(fexp2(pa[10]), fexp2(pa[11]));
          uint32_t p6 = pkrtz(fexp2(pa[12]), fexp2(pa[13]));
          uint32_t p7 = pkrtz(fexp2(pa[14]), fexp2(pa[15]));
          asm volatile("v_permlane32_swap_b32 %0, %1" : "+v"(p0), "+v"(p2));
          asm volatile("v_permlane32_swap_b32 %0, %1" : "+v"(p1), "+v"(p3));
          asm volatile("v_permlane32_swap_b32 %0, %1" : "+v"(p4), "+v"(p6));
          asm volatile("v_permlane32_swap_b32 %0, %1" : "+v"(p5), "+v"(p7));
          union { uint32_t u[4]; half8 hh; } f0, f1;
          f0.u[0] = p0; f0.u[1] = p1; f0.u[2] = p2; f0.u[3] = p3;
          f1.u[0] = p4; f1.u[1] = p5; f1.u[2] = p6; f1.u[3] = p7;
          int sblk = sp * 2 + Y;
          *(half8*)(pd + ((tp * 2 + 0) * 4 + sblk) * 512 + lane * 8) = f0.hh;
          *(half8*)(pd + ((tp * 2 + 1) * 4 + sblk) * 512 + lane * 8) = f1.hh;
        }
      }
    }
  } else {
    // ================= consumers: c-block cw (64) x s full 128 ==============
    int cw = w - 4;
    // V staging: 8 units/wave, rows c = cw*64 + i*8 + (lane>>3)
    int voff[8];
#pragma unroll
    for (int i = 0; i < 8; ++i) {
      int c = cw * 64 + i * 8 + (lane >> 3);
      voff[i] = c * S_DIM + (((lane & 7) ^ (c & 7)) * 8);
    }
    int vu[4];
#pragma unroll
    for (int k = 0; k < 4; ++k) vu[k] = ((k * 2 + h) ^ (l31 & 7)) * 8;
    int vrow0 = (cw * 64 + l31) * 64;
    int vrow1 = (cw * 64 + 32 + l31) * 64;
    f32x16 acc0[4] = {}, acc1[4] = {};
    for (int it = 0; it <= 64; ++it) {
      asm volatile("s_waitcnt vmcnt(0) lgkmcnt(0)" ::: "memory");
      __builtin_amdgcn_s_barrier();
      if (it < 64) {
        // issue V(it) (consumed next iteration)
        const _Float16* vb = vvn + it * 64;
        _Float16* vd = &Vb[it & 1][0];
#pragma unroll
        for (int i = 0; i < 8; ++i) glds16(vb + voff[i], vd + cw * 4096 + i * 512);
      }
      if (it > 0) {
        const _Float16* vc = &Vb[(it - 1) & 1][0];
        const _Float16* pc = &Pb[(it - 1) & 1][0];
        __builtin_amdgcn_s_setprio(1);
#pragma unroll
        for (int k = 0; k < 4; ++k) {
          half8 a0 = *(const half8*)(vc + vrow0 + vu[k]);
          half8 a1 = *(const half8*)(vc + vrow1 + vu[k]);
#pragma unroll
          for (int sbk = 0; sbk < 4; ++sbk) {
            half8 pb = *(const half8*)(pc + (k * 4 + sbk) * 512 + lane * 8);
            acc0[sbk] = mfma32(a0, pb, acc0[sbk]);
            acc1[sbk] = mfma32(a1, pb, acc1[sbk]);
          }
        }
        __builtin_amdgcn_s_setprio(0);
      }
    }
    // epilogue: O += acc/256 (residual already in outp)
    float* ob = outp + (size_t)n * C_DIM * S_DIM + (size_t)sb * 128 + l31;
#pragma unroll
    for (int sbk = 0; sbk < 4; ++sbk)
#pragma unroll
      for (int rr = 0; rr < 16; ++rr) {
        int c = cw * 64 + (rr & 3) + 8 * (rr >> 2) + 4 * h;
        ob[(size_t)c * S_DIM + sbk * 32] += acc0[sbk][rr] * 0.00390625f;
        ob[(size_t)(c + 32) * S_DIM + sbk * 32] += acc1[sbk][rr] * 0.00390625f;
      }
  }
}

extern "C" void kernel_launch(void* const* d_in, const int* in_sizes, int n_in,
                              void* d_out, int out_size, void* d_ws, size_t ws_size,
                              hipStream_t stream) {
  const float* x  = (const float*)d_in[0];
  const float* Wq = (const float*)d_in[1];
  const float* Wk = (const float*)d_in[2];
  const float* Wv = (const float*)d_in[3];
  const float* Wl = (const float*)d_in[4];
  float* out = (float*)d_out;
  char* base = (char*)d_ws;
  const size_t MB = 1024 * 1024;
  _Float16* xT = (_Float16*)(base);
  _Float16* qT = (_Float16*)(base + 16 * MB);
  _Float16* kT = (_Float16*)(base + 32 * MB);
  _Float16* vv = (_Float16*)(base + 48 * MB);
  _Float16* Wh = (_Float16*)(base + 64 * MB);
  float* lpart = (float*)(base + 64 * MB + 524288);

  k_transpose<<<dim3(64, 4, N_B), dim3(256), 0, stream>>>(x, xT);
  k_wconv<<<dim3(64), dim3(256), 0, stream>>>(Wq, Wk, Wv, Wl, Wh);
  k_proj<<<dim3(64, 32), dim3(256), 0, stream>>>(xT, Wh, qT, kT, vv, out);
  k_rowsum<<<dim3(256), dim3(512), 0, stream>>>(qT, kT, lpart);
  k_vscale<<<dim3(4096), dim3(256), 0, stream>>>(vv, lpart);
  k_attn<<<dim3(256), dim3(512), 0, stream>>>(qT, kT, vv, out);
}

// Round 14
// 264.900 us; speedup vs baseline: 1.0100x; 1.0100x over previous
//
#include <hip/hip_runtime.h>
#include <hip/hip_bf16.h>
#include <hip/hip_fp16.h>

typedef __attribute__((ext_vector_type(8))) _Float16 half8;
typedef __attribute__((ext_vector_type(2))) __fp16 fp16x2;
typedef __attribute__((ext_vector_type(4))) float f32x4;
typedef __attribute__((ext_vector_type(16))) float f32x16;

#define N_B 8
#define C_DIM 256
#define S_DIM 4096

__device__ __forceinline__ _Float16 f2h(float f) { return (_Float16)f; }

__device__ __forceinline__ f32x4 mfma16(half8 a, half8 b, f32x4 c) {
  return __builtin_amdgcn_mfma_f32_16x16x32_f16(a, b, c, 0, 0, 0);
}
__device__ __forceinline__ f32x16 mfma32(half8 a, half8 b, f32x16 c) {
  return __builtin_amdgcn_mfma_f32_32x32x16_f16(a, b, c, 0, 0, 0);
}

__device__ __forceinline__ void glds16(const _Float16* src, _Float16* dst) {
  __builtin_amdgcn_global_load_lds(
      (const __attribute__((address_space(1))) void*)src,
      (__attribute__((address_space(3))) void*)dst, 16, 0, 0);
}

__device__ __forceinline__ uint32_t pkrtz(float a, float b) {
  union { fp16x2 h; uint32_t u; } cv;
  cv.h = __builtin_amdgcn_cvt_pkrtz(a, b);
  return cv.u;
}

// raw hardware exp2 via the compiler-known builtin (v_exp_f32, TRANS op)
__device__ __forceinline__ float fexp2(float x) {
  return __builtin_amdgcn_exp2f(x);
}

// ---- K0: transpose x (n,C,S) fp32 -> xT (n,S,C) fp16 ----
__global__ __launch_bounds__(256) void k_transpose(const float* __restrict__ x,
                                                   _Float16* __restrict__ xT) {
  __shared__ _Float16 tile[64][65];
  int n = blockIdx.z, cb = blockIdx.y * 64, sb = blockIdx.x * 64;
  const float* xp = x + ((size_t)n * C_DIM + cb) * S_DIM + sb;
  int t = threadIdx.x;
#pragma unroll
  for (int p = 0; p < 4; ++p) {
    int row = p * 16 + (t >> 4);
    int col = (t & 15) * 4;
    float4 v4 = *(const float4*)(xp + (size_t)row * S_DIM + col);
    tile[row][col + 0] = f2h(v4.x);
    tile[row][col + 1] = f2h(v4.y);
    tile[row][col + 2] = f2h(v4.z);
    tile[row][col + 3] = f2h(v4.w);
  }
  __syncthreads();
  _Float16* op = xT + ((size_t)n * S_DIM + sb) * C_DIM + cb;
#pragma unroll
  for (int p = 0; p < 2; ++p) {
    int srow = p * 32 + (t >> 3);
    int ccol = (t & 7) * 8;
    half8 u;
#pragma unroll
    for (int i = 0; i < 8; ++i) u[i] = tile[ccol + i][srow];
    *(half8*)(op + (size_t)srow * C_DIM + ccol) = u;
  }
}

// ---- K0b: weights fp32 -> fp16; Wq pre-scaled by log2(e) ----
__global__ __launch_bounds__(256) void k_wconv(const float* __restrict__ w0, const float* __restrict__ w1,
                                               const float* __restrict__ w2, const float* __restrict__ w3,
                                               _Float16* __restrict__ Wh) {
  int idx = blockIdx.x * 256 + threadIdx.x;
  const float* srcs[4] = {w0, w1, w2, w3};
#pragma unroll
  for (int j = 0; j < 4; ++j) {
    const float* s = srcs[j];
    float sc = (j == 0) ? 1.4426950408889634f : 1.0f;
    for (int i = idx; i < C_DIM * C_DIM; i += 16384) Wh[j * C_DIM * C_DIM + i] = f2h(s[i] * sc);
  }
}

// ---- K1: projection GEMMs ----
__global__ __launch_bounds__(256) void k_proj(const _Float16* __restrict__ xT, const _Float16* __restrict__ Wh,
                                              _Float16* __restrict__ qT, _Float16* __restrict__ kT,
                                              _Float16* __restrict__ vv, float* __restrict__ outp) {
  __shared__ __align__(16) _Float16 As[128][72];
  __shared__ __align__(16) _Float16 Bs[128][72];
  int job = blockIdx.y;
  int n = job >> 2, j = job & 3;
  const _Float16* A;
  const _Float16* B;
  int tm, tn, ldo;
  _Float16* obf = nullptr;
  float* of32 = nullptr;
  const _Float16* xTn = xT + (size_t)n * S_DIM * C_DIM;
  if (j < 2) {
    A = xTn;
    B = Wh + j * C_DIM * C_DIM;
    tm = blockIdx.x >> 1; tn = blockIdx.x & 1;
    obf = (j == 0 ? qT : kT) + (size_t)n * S_DIM * C_DIM;
    ldo = C_DIM;
  } else {
    A = Wh + j * C_DIM * C_DIM;
    B = xTn;
    tm = blockIdx.x >> 5; tn = blockIdx.x & 31;
    ldo = S_DIM;
    if (j == 2) obf = vv + (size_t)n * C_DIM * S_DIM;
    else of32 = outp + (size_t)n * C_DIM * S_DIM;
  }
  int t = threadIdx.x, w = t >> 6, lane = t & 63, r = lane & 15, q = lane >> 4;
  int wm = w >> 1, wn = w & 1;
  f32x4 acc[4][4] = {};
  for (int kc = 0; kc < 4; ++kc) {
#pragma unroll
    for (int p = 0; p < 4; ++p) {
      int row = p * 32 + (t >> 3), c8 = (t & 7) * 8;
      *(half8*)&As[row][c8] = *(const half8*)(A + (size_t)(tm * 128 + row) * C_DIM + kc * 64 + c8);
      *(half8*)&Bs[row][c8] = *(const half8*)(B + (size_t)(tn * 128 + row) * C_DIM + kc * 64 + c8);
    }
    __syncthreads();
#pragma unroll
    for (int kk = 0; kk < 2; ++kk) {
      half8 a[4], b[4];
#pragma unroll
      for (int mi = 0; mi < 4; ++mi) a[mi] = *(const half8*)&As[wm * 64 + mi * 16 + r][kk * 32 + q * 8];
#pragma unroll
      for (int ni = 0; ni < 4; ++ni) b[ni] = *(const half8*)&Bs[wn * 64 + ni * 16 + r][kk * 32 + q * 8];
#pragma unroll
      for (int mi = 0; mi < 4; ++mi)
#pragma unroll
        for (int ni = 0; ni < 4; ++ni)
          acc[mi][ni] = mfma16(a[mi], b[ni], acc[mi][ni]);
    }
    __syncthreads();
  }
#pragma unroll
  for (int mi = 0; mi < 4; ++mi)
#pragma unroll
    for (int ni = 0; ni < 4; ++ni)
#pragma unroll
      for (int jj = 0; jj < 4; ++jj) {
        int row = tm * 128 + wm * 64 + mi * 16 + q * 4 + jj;
        int col = tn * 128 + wn * 64 + ni * 16 + r;
        float val = acc[mi][ni][jj];
        if (obf) obf[(size_t)row * ldo + col] = f2h(val);
        else of32[(size_t)row * ldo + col] = val;
      }
}

// ---- K2: partial row sums (round-10 verified: mfma16, hoisted addrs) ----
__global__ __launch_bounds__(512, 2) void k_rowsum(const _Float16* __restrict__ qT,
                                                   const _Float16* __restrict__ kT,
                                                   float* __restrict__ lpart) {
  __shared__ __align__(16) _Float16 Qs[2][64 * 256];
  int bid = blockIdx.x;
  int n = bid & 7, rest = bid >> 3;
  int tb = rest & 7, sq = rest >> 3;
  int t = threadIdx.x, w = t >> 6, lane = t & 63, r = lane & 15, q = lane >> 4;
  const _Float16* kp = kT + ((size_t)n * S_DIM + tb * 512 + w * 64) * C_DIM;
  const _Float16* qp = qT + ((size_t)n * S_DIM + sq * 1024) * C_DIM;
  half8 kf[4][8];
#pragma unroll
  for (int mt = 0; mt < 4; ++mt)
#pragma unroll
    for (int k = 0; k < 8; ++k)
      kf[mt][k] = *(const half8*)(kp + (size_t)(mt * 16 + r) * C_DIM + k * 32 + q * 8);
  int d0 = w * 1024 + lane * 16;
  int qswz = d0 ^ ((((w * 2) + (lane >> 5)) & 7) << 4);
  const char* qsrc0 = (const char*)qp + qswz;
  int rb = r * 256, rx = (r & 7) << 3, qq8 = q * 8;
  int kx[8];
#pragma unroll
  for (int k = 0; k < 8; ++k) kx[k] = (k * 32 + qq8) ^ rx;
#pragma unroll
  for (int i = 0; i < 4; ++i)
    glds16((const _Float16*)(qsrc0 + i * 8192), &Qs[0][i * 4096 + w * 512]);
  asm volatile("s_waitcnt vmcnt(0)" ::: "memory");
  __builtin_amdgcn_s_barrier();
  float sums[4][4] = {};
  for (int sc = 0; sc < 16; ++sc) {
    int cur = sc & 1, nxt = cur ^ 1;
    int sn = (sc + 1) & 15;
    const char* qb = qsrc0 + (size_t)sn * 32768;
#pragma unroll
    for (int i = 0; i < 4; ++i)
      glds16((const _Float16*)(qb + i * 8192), &Qs[nxt][i * 4096 + w * 512]);
    __builtin_amdgcn_s_setprio(1);
#pragma unroll
    for (int st = 0; st < 4; ++st) {
      f32x4 acc[4] = {};
#pragma unroll
      for (int k = 0; k < 8; ++k) {
        half8 b = *(const half8*)&Qs[cur][rb + st * 4096 + kx[k]];
#pragma unroll
        for (int mt = 0; mt < 4; ++mt) acc[mt] = mfma16(kf[mt][k], b, acc[mt]);
      }
#pragma unroll
      for (int mt = 0; mt < 4; ++mt)
#pragma unroll
        for (int jj = 0; jj < 4; ++jj) sums[mt][jj] += fexp2(acc[mt][jj]);
    }
    __builtin_amdgcn_s_setprio(0);
    asm volatile("s_waitcnt vmcnt(0) lgkmcnt(0)" ::: "memory");
    __builtin_amdgcn_s_barrier();
  }
#pragma unroll
  for (int mt = 0; mt < 4; ++mt)
#pragma unroll
    for (int jj = 0; jj < 4; ++jj) {
      float v = sums[mt][jj];
      v += __shfl_xor(v, 1);
      v += __shfl_xor(v, 2);
      v += __shfl_xor(v, 4);
      v += __shfl_xor(v, 8);
      if (r == 0)
        lpart[((size_t)sq * N_B + n) * S_DIM + tb * 512 + w * 64 + mt * 16 + q * 4 + jj] = v;
    }
}

// ---- K2b: fold 1/l into V (4 partials) ----
__global__ __launch_bounds__(256) void k_vscale(_Float16* __restrict__ vv, const float* __restrict__ lpart) {
  int idx = blockIdx.x * 256 + threadIdx.x;
  int t8 = idx & 511;
  int cn = idx >> 9;
  int n = cn >> 8;
  size_t voff = (size_t)cn * S_DIM + t8 * 8;
  half8 v = *(half8*)(vv + voff);
  const float* lp = lpart + (size_t)n * S_DIM + t8 * 8;
#pragma unroll
  for (int j = 0; j < 8; ++j) {
    float s = lp[j] + lp[N_B * S_DIM + j] + lp[2 * N_B * S_DIM + j] + lp[3 * N_B * S_DIM + j];
    v[j] = f2h((float)v[j] * (4096.0f / s));
  }
  *(half8*)(vv + voff) = v;
}

// ---- K3: attention (round-10 verified): 16 waves producer/consumer,
// issue-early glds + counted vmcnt(4), one barrier per iteration. ----
__global__ __launch_bounds__(1024, 4) void k_attn(const _Float16* __restrict__ qT,
                                                  const _Float16* __restrict__ kT,
                                                  const _Float16* __restrict__ vv,
                                                  float* __restrict__ outp) {
  __shared__ __align__(16) _Float16 Kb[2][16384];  // [t64][c256] XOR-swz(32)
  __shared__ __align__(16) _Float16 Vb[2][16384];  // [c256][t64] XOR-swz(8)
  __shared__ __align__(16) _Float16 Pb[2][8192];   // [k4][st4][lane64][8]
  int bid = blockIdx.x;
  int n = bid & 7, sb = bid >> 3;
  int tid = threadIdx.x, w = tid >> 6, lane = tid & 63;
  int l31 = lane & 31, h = lane >> 5;
  const _Float16* kpn = kT + (size_t)n * S_DIM * C_DIM;
  const _Float16* vvn = vv + (size_t)n * C_DIM * S_DIM;

  if (w < 8) {
    // ================= producers =================
    int tp = w >> 2, sp = w & 3;
    const _Float16* qp = qT + ((size_t)n * S_DIM + sb * 128 + sp * 32 + l31) * C_DIM;
    half8 qreg[16];
#pragma unroll
    for (int cs = 0; cs < 16; ++cs) qreg[cs] = *(const half8*)(qp + cs * 16 + h * 8);
    int koff[4];
#pragma unroll
    for (int i = 0; i < 4; ++i) {
      int r = w * 8 + i * 2 + h;
      koff[i] = r * C_DIM + ((l31 ^ (r & 31)) * 8);
    }
    int tko = (tp * 32 + l31) * C_DIM;
    int kaddr[16];
#pragma unroll
    for (int cs = 0; cs < 16; ++cs) kaddr[cs] = tko + 8 * ((2 * cs + h) ^ l31);
    // prologue: issue K(0) (confirmed at it=0's wait)
#pragma unroll
    for (int i = 0; i < 4; ++i) glds16(kpn + koff[i], &Kb[0][w * 2048 + i * 512]);
    for (int it = 0; it <= 64; ++it) {
      if (it < 63) {
        // issue K(it+1) -> Kb[(it+1)&1]; confirm K(it) (4 newest stay in flight)
        const _Float16* kb = kpn + (size_t)(it + 1) * 64 * C_DIM;
        _Float16* kd = &Kb[(it + 1) & 1][0];
#pragma unroll
        for (int i = 0; i < 4; ++i) glds16(kb + koff[i], kd + w * 2048 + i * 512);
        asm volatile("s_waitcnt vmcnt(4) lgkmcnt(0)" ::: "memory");
      } else {
        asm volatile("s_waitcnt vmcnt(0) lgkmcnt(0)" ::: "memory");
      }
      __builtin_amdgcn_s_barrier();
      if (it < 64) {
        const _Float16* kc = &Kb[it & 1][0];
        f32x16 pacc;
#pragma unroll
        for (int i = 0; i < 16; ++i) pacc[i] = -4.0f;
        __builtin_amdgcn_s_setprio(1);
#pragma unroll
        for (int cs = 0; cs < 16; ++cs) {
          half8 a = *(const half8*)(kc + kaddr[cs]);
          pacc = mfma32(a, qreg[cs], pacc);
        }
        __builtin_amdgcn_s_setprio(0);
        uint32_t p0 = pkrtz(fexp2(pacc[0]), fexp2(pacc[1]));
        uint32_t p1 = pkrtz(fexp2(pacc[2]), fexp2(pacc[3]));
        uint32_t p2 = pkrtz(fexp2(pacc[4]), fexp2(pacc[5]));
        uint32_t p3 = pkrtz(fexp2(pacc[6]), fexp2(pacc[7]));
        uint32_t p4 = pkrtz(fexp2(pacc[8]), fexp2(pacc[9]));
        uint32_t p5 = pkrtz(fexp2(pacc[10]), fexp2(pacc[11]));
        uint32_t p6 = pkrtz(fexp2(pacc[12]), fexp2(pacc[13]));
        uint32_t p7 = pkrtz(fexp2(pacc[14]), fexp2(pacc[15]));
        asm volatile("v_permlane32_swap_b32 %0, %1" : "+v"(p0), "+v"(p2));
        asm volatile("v_permlane32_swap_b32 %0, %1" : "+v"(p1), "+v"(p3));
        asm volatile("v_permlane32_swap_b32 %0, %1" : "+v"(p4), "+v"(p6));
        asm volatile("v_permlane32_swap_b32 %0, %1" : "+v"(p5), "+v"(p7));
        union { uint32_t u[4]; half8 hh; } f0, f1;
        f0.u[0] = p0; f0.u[1] = p1; f0.u[2] = p2; f0.u[3] = p3;
        f1.u[0] = p4; f1.u[1] = p5; f1.u[2] = p6; f1.u[3] = p7;
        _Float16* pd = &Pb[it & 1][0];
        *(half8*)(pd + ((tp * 2 + 0) * 4 + sp) * 512 + lane * 8) = f0.hh;
        *(half8*)(pd + ((tp * 2 + 1) * 4 + sp) * 512 + lane * 8) = f1.hh;
      }
    }
  } else {
    // ================= consumers =================
    int cw = w - 8, cq = cw >> 1, sq = cw & 1;
    int voff[4];
#pragma unroll
    for (int i = 0; i < 4; ++i) {
      int c = cw * 32 + i * 8 + (lane >> 3);
      voff[i] = c * S_DIM + (((lane & 7) ^ (c & 7)) * 8);
    }
    int vu[4];
#pragma unroll
    for (int k = 0; k < 4; ++k) vu[k] = ((k * 2 + h) ^ (l31 & 7)) * 8;
    int vrow0 = (cq * 64 + l31) * 64;
    int vrow1 = (cq * 64 + 32 + l31) * 64;
    f32x16 acc00 = {}, acc01 = {}, acc10 = {}, acc11 = {};
    for (int it = 0; it <= 64; ++it) {
      if (it < 64) {
        // issue V(it) -> Vb[it&1]; confirm V(it-1) (4 newest stay in flight)
        const _Float16* vb = vvn + it * 64;
        _Float16* vd = &Vb[it & 1][0];
#pragma unroll
        for (int i = 0; i < 4; ++i) glds16(vb + voff[i], vd + cw * 2048 + i * 512);
        asm volatile("s_waitcnt vmcnt(4) lgkmcnt(0)" ::: "memory");
      } else {
        asm volatile("s_waitcnt vmcnt(0) lgkmcnt(0)" ::: "memory");
      }
      __builtin_amdgcn_s_barrier();
      if (it > 0) {
        const _Float16* vc = &Vb[(it - 1) & 1][0];
        const _Float16* pc = &Pb[(it - 1) & 1][0];
        __builtin_amdgcn_s_setprio(1);
#pragma unroll
        for (int k = 0; k < 4; ++k) {
          half8 pb0 = *(const half8*)(pc + (k * 4 + sq * 2 + 0) * 512 + lane * 8);
          half8 pb1 = *(const half8*)(pc + (k * 4 + sq * 2 + 1) * 512 + lane * 8);
          half8 a0 = *(const half8*)(vc + vrow0 + vu[k]);
          half8 a1 = *(const half8*)(vc + vrow1 + vu[k]);
          acc00 = mfma32(a0, pb0, acc00);
          acc01 = mfma32(a0, pb1, acc01);
          acc10 = mfma32(a1, pb0, acc10);
          acc11 = mfma32(a1, pb1, acc11);
        }
        __builtin_amdgcn_s_setprio(0);
      }
    }
    // epilogue: O += acc/256 (residual already in outp)
    float* ob = outp + (size_t)n * C_DIM * S_DIM + (size_t)sb * 128 + sq * 64 + l31;
#pragma unroll
    for (int rr = 0; rr < 16; ++rr) {
      int c = cq * 64 + (rr & 3) + 8 * (rr >> 2) + 4 * h;
      ob[(size_t)c * S_DIM + 0]  += acc00[rr] * 0.00390625f;
      ob[(size_t)c * S_DIM + 32] += acc01[rr] * 0.00390625f;
      ob[(size_t)(c + 32) * S_DIM + 0]  += acc10[rr] * 0.00390625f;
      ob[(size_t)(c + 32) * S_DIM + 32] += acc11[rr] * 0.00390625f;
    }
  }
}

extern "C" void kernel_launch(void* const* d_in, const int* in_sizes, int n_in,
                              void* d_out, int out_size, void* d_ws, size_t ws_size,
                              hipStream_t stream) {
  const float* x  = (const float*)d_in[0];
  const float* Wq = (const float*)d_in[1];
  const float* Wk = (const float*)d_in[2];
  const float* Wv = (const float*)d_in[3];
  const float* Wl = (const float*)d_in[4];
  float* out = (float*)d_out;
  char* base = (char*)d_ws;
  const size_t MB = 1024 * 1024;
  _Float16* xT = (_Float16*)(base);
  _Float16* qT = (_Float16*)(base + 16 * MB);
  _Float16* kT = (_Float16*)(base + 32 * MB);
  _Float16* vv = (_Float16*)(base + 48 * MB);
  _Float16* Wh = (_Float16*)(base + 64 * MB);
  float* lpart = (float*)(base + 64 * MB + 524288);  // 512KB, ends at 65MB

  k_transpose<<<dim3(64, 4, N_B), dim3(256), 0, stream>>>(x, xT);
  k_wconv<<<dim3(64), dim3(256), 0, stream>>>(Wq, Wk, Wv, Wl, Wh);
  k_proj<<<dim3(64, 32), dim3(256), 0, stream>>>(xT, Wh, qT, kT, vv, out);
  k_rowsum<<<dim3(256), dim3(512), 0, stream>>>(qT, kT, lpart);
  k_vscale<<<dim3(4096), dim3(256), 0, stream>>>(vv, lpart);
  k_attn<<<dim3(256), dim3(1024), 0, stream>>>(qT, kT, vv, out);
}